// Round 6
// baseline (2992.167 us; speedup 1.0000x reference)
//
#include <hip/hip_runtime.h>

#define BTOT 8192
#define T 512
#define INW 8
#define HID 64
#define NB 8          // batch elems per block
#define TS 128        // timesteps per staged x-chunk
#define XSEG4 257     // float4 per xbuf batch segment (256 + 1 pad)
#define GROW 9        // gate_t row stride (8 + 1 pad)

__device__ __forceinline__ float fast_rcp(float x) { return __builtin_amdgcn_rcpf(x); }
__device__ __forceinline__ float sigm_f(float x) { return fast_rcp(1.0f + __expf(-x)); }
__device__ __forceinline__ float tanh_f(float x) { return 1.0f - 2.0f * fast_rcp(__expf(2.0f * x) + 1.0f); }

// R=2 rows x K=16 slice per thread: 8 FMA per ds_read_b128 (was 1:1 in r5).
// LDS padded to 56.4KB -> 2 blocks/CU -> backend targets 4 waves/SIMD ->
// 128-VGPR budget (occupancy-target model validated in rounds 3-5).
__attribute__((amdgpu_waves_per_eu(2, 4)))
__global__ __launch_bounds__(512) void lstm_fused_kernel(
    const float* __restrict__ x,      // [B, T, IN]
    const float* __restrict__ W_ih,   // [4H, IN]
    const float* __restrict__ W_hh,   // [4H, H]
    const float* __restrict__ b_ih,   // [4H]
    const float* __restrict__ b_hh,   // [4H]
    const float* __restrict__ W_fc,   // [2, H]
    const float* __restrict__ b_fc,   // [2]
    float* __restrict__ out)          // [B, 2]
{
    __shared__ alignas(16) float xbuf[NB * XSEG4 * 4];   // 32.9 KB
    __shared__ alignas(16) float h_lds[NB * HID];        // 2 KB
    __shared__ alignas(16) float gate_t[256 * GROW];     // 9.2 KB, [row][b]
    __shared__ float lds_pad[3072];                      // 12 KB occupancy lever

    const int tid = threadIdx.x;       // 0..511
    const int rp  = tid >> 2;          // row-pair 0..127
    const int kq  = tid & 3;           // k-quarter 0..3
    const int r0  = rp * 2;            // rows r0, r0+1
    const int batch0 = blockIdx.x * NB;

    // keep the pad allocation alive (condition never true at runtime)
    if (out == nullptr) lds_pad[tid] = 0.0f;

    // ---- persistent weights: W_hh[r0..r0+1][16kq..16kq+16) = 8 named f4 ----
    const float4* Wq = reinterpret_cast<const float4*>(W_hh);
    float4 u0 = Wq[r0 * 16 + kq * 4 + 0];
    float4 u1 = Wq[r0 * 16 + kq * 4 + 1];
    float4 u2 = Wq[r0 * 16 + kq * 4 + 2];
    float4 u3 = Wq[r0 * 16 + kq * 4 + 3];
    float4 v0 = Wq[(r0 + 1) * 16 + kq * 4 + 0];
    float4 v1 = Wq[(r0 + 1) * 16 + kq * 4 + 1];
    float4 v2 = Wq[(r0 + 1) * 16 + kq * 4 + 2];
    float4 v3 = Wq[(r0 + 1) * 16 + kq * 4 + 3];
    // full W_ih rows (this lane activates batch pair {2kq, 2kq+1})
    float4 wiA0 = reinterpret_cast<const float4*>(W_ih)[r0 * 2 + 0];
    float4 wiA1 = reinterpret_cast<const float4*>(W_ih)[r0 * 2 + 1];
    float4 wiB0 = reinterpret_cast<const float4*>(W_ih)[(r0 + 1) * 2 + 0];
    float4 wiB1 = reinterpret_cast<const float4*>(W_ih)[(r0 + 1) * 2 + 1];
    const float bias0 = b_ih[r0] + b_hh[r0];
    const float bias1 = b_ih[r0 + 1] + b_hh[r0 + 1];

    const int bA = 2 * kq, bB = 2 * kq + 1;
    const bool k0 = (kq & 1) != 0;
    const bool k1 = (kq & 2) != 0;

    // update-phase mapping: wave bb owns batch bb; lane j = hidden index
    const int j  = tid & 63;
    const int bb = tid >> 6;           // 0..7
    float c = 0.0f;

    // wave-uniform: rows 32w..32w+31; tanh gate = rows 128..191 = waves 4,5
    const bool is_tanh_gate = (r0 >= 128 && r0 < 192);

    h_lds[tid] = 0.0f;                 // NB*HID == 512

    const float4* h4 = reinterpret_cast<const float4*>(h_lds);
    const float4* xb4 = reinterpret_cast<const float4*>(xbuf);

    #pragma unroll 1
    for (int tc = 0; tc < T / TS; ++tc) {
        __syncthreads();               // xbuf free; covers h init at tc=0
        // ---- stage x chunk: 2048 f4, 4 iters, coalesced, padded segments ----
        {
            const float4* xs = reinterpret_cast<const float4*>(x);
            float4* xd = reinterpret_cast<float4*>(xbuf);
            #pragma unroll
            for (int it = 0; it < 4; ++it) {
                int idx = it * 512 + tid;
                int b = idx >> 8;               // 256 f4 per segment
                int l = idx & 255;
                xd[b * XSEG4 + l] =
                    xs[(size_t)(batch0 + b) * (T * INW / 4) + tc * (TS * INW / 4) + l];
            }
        }
        __syncthreads();

        #pragma unroll 1
        for (int tt = 0; tt < TS; ++tt) {
            // ---- recurrent partial dots: 2 rows x 16 k x 8 b ----
            float acc0[NB], acc1[NB];
            #pragma unroll
            for (int b = 0; b < NB; ++b) { acc0[b] = 0.0f; acc1[b] = 0.0f; }

#define KKSTEP(i, W0, W1)                                                \
            {                                                            \
                _Pragma("unroll")                                        \
                for (int b = 0; b < NB; ++b) {                           \
                    float4 hv = h4[b * 16 + kq * 4 + i];                 \
                    float a = acc0[b], s = acc1[b];                      \
                    a = fmaf(W0.x, hv.x, a);  s = fmaf(W1.x, hv.x, s);   \
                    a = fmaf(W0.y, hv.y, a);  s = fmaf(W1.y, hv.y, s);   \
                    a = fmaf(W0.z, hv.z, a);  s = fmaf(W1.z, hv.z, s);   \
                    a = fmaf(W0.w, hv.w, a);  s = fmaf(W1.w, hv.w, s);   \
                    acc0[b] = a; acc1[b] = s;                            \
                }                                                        \
            }
            KKSTEP(0, u0, v0)
            KKSTEP(1, u1, v1)
            KKSTEP(2, u2, v2)
            KKSTEP(3, u3, v3)
#undef KKSTEP

            // ---- combine k-quarters within each quad (DPP shuffles) ----
            #pragma unroll
            for (int b = 0; b < NB; ++b) {
                acc0[b] += __shfl_xor(acc0[b], 1, 64);
                acc0[b] += __shfl_xor(acc0[b], 2, 64);
                acc1[b] += __shfl_xor(acc1[b], 1, 64);
                acc1[b] += __shfl_xor(acc1[b], 2, 64);
            }

            // ---- select this lane's 4 owned (row, b) values: b = bA, bB ----
            float t0, t1;
            t0 = k0 ? acc0[2] : acc0[0];
            t1 = k0 ? acc0[6] : acc0[4];
            float p00 = k1 ? t1 : t0;
            t0 = k0 ? acc0[3] : acc0[1];
            t1 = k0 ? acc0[7] : acc0[5];
            float p01 = k1 ? t1 : t0;
            t0 = k0 ? acc1[2] : acc1[0];
            t1 = k0 ? acc1[6] : acc1[4];
            float p10 = k1 ? t1 : t0;
            t0 = k0 ? acc1[3] : acc1[1];
            t1 = k0 ? acc1[7] : acc1[5];
            float p11 = k1 ? t1 : t0;

            // ---- x-projection + bias for owned (row, b) ----
            {
                float4 xA0 = xb4[bA * XSEG4 + tt * 2];
                float4 xA1 = xb4[bA * XSEG4 + tt * 2 + 1];
                float4 xB0 = xb4[bB * XSEG4 + tt * 2];
                float4 xB1 = xb4[bB * XSEG4 + tt * 2 + 1];
                p00 += bias0; p01 += bias0; p10 += bias1; p11 += bias1;
                p00 = fmaf(wiA0.x, xA0.x, p00); p00 = fmaf(wiA0.y, xA0.y, p00);
                p00 = fmaf(wiA0.z, xA0.z, p00); p00 = fmaf(wiA0.w, xA0.w, p00);
                p00 = fmaf(wiA1.x, xA1.x, p00); p00 = fmaf(wiA1.y, xA1.y, p00);
                p00 = fmaf(wiA1.z, xA1.z, p00); p00 = fmaf(wiA1.w, xA1.w, p00);
                p01 = fmaf(wiA0.x, xB0.x, p01); p01 = fmaf(wiA0.y, xB0.y, p01);
                p01 = fmaf(wiA0.z, xB0.z, p01); p01 = fmaf(wiA0.w, xB0.w, p01);
                p01 = fmaf(wiA1.x, xB1.x, p01); p01 = fmaf(wiA1.y, xB1.y, p01);
                p01 = fmaf(wiA1.z, xB1.z, p01); p01 = fmaf(wiA1.w, xB1.w, p01);
                p10 = fmaf(wiB0.x, xA0.x, p10); p10 = fmaf(wiB0.y, xA0.y, p10);
                p10 = fmaf(wiB0.z, xA0.z, p10); p10 = fmaf(wiB0.w, xA0.w, p10);
                p10 = fmaf(wiB1.x, xA1.x, p10); p10 = fmaf(wiB1.y, xA1.y, p10);
                p10 = fmaf(wiB1.z, xA1.z, p10); p10 = fmaf(wiB1.w, xA1.w, p10);
                p11 = fmaf(wiB0.x, xB0.x, p11); p11 = fmaf(wiB0.y, xB0.y, p11);
                p11 = fmaf(wiB0.z, xB0.z, p11); p11 = fmaf(wiB0.w, xB0.w, p11);
                p11 = fmaf(wiB1.x, xB1.x, p11); p11 = fmaf(wiB1.y, xB1.y, p11);
                p11 = fmaf(wiB1.z, xB1.z, p11); p11 = fmaf(wiB1.w, xB1.w, p11);
            }

            // ---- activation (wave-uniform) + write to gate_t[row][b] ----
            {
                float a00, a01, a10, a11;
                if (is_tanh_gate) {
                    a00 = tanh_f(p00); a01 = tanh_f(p01);
                    a10 = tanh_f(p10); a11 = tanh_f(p11);
                } else {
                    a00 = sigm_f(p00); a01 = sigm_f(p01);
                    a10 = sigm_f(p10); a11 = sigm_f(p11);
                }
                gate_t[r0 * GROW + bA]       = a00;
                gate_t[r0 * GROW + bB]       = a01;
                gate_t[(r0 + 1) * GROW + bA] = a10;
                gate_t[(r0 + 1) * GROW + bB] = a11;
            }
            __syncthreads();

            // ---- update phase: one state (bb, j) per thread ----
            {
                float iv = gate_t[j * GROW + bb];
                float fv = gate_t[(64 + j) * GROW + bb];
                float gv = gate_t[(128 + j) * GROW + bb];
                float ov = gate_t[(192 + j) * GROW + bb];
                c = fmaf(fv, c, iv * gv);
                h_lds[bb * HID + j] = ov * tanh_f(c);
            }
            __syncthreads();
        }
    }

    // ---- final FC: wave bb reduces batch elem bb over 64 lanes ----
    {
        float h  = h_lds[bb * HID + j];
        float p0 = h * W_fc[j];
        float p1 = h * W_fc[HID + j];
        #pragma unroll
        for (int off = 32; off > 0; off >>= 1) {
            p0 += __shfl_down(p0, off, 64);
            p1 += __shfl_down(p1, off, 64);
        }
        if (j == 0) {
            out[(size_t)(batch0 + bb) * 2 + 0] = p0 + b_fc[0];
            out[(size_t)(batch0 + bb) * 2 + 1] = p1 + b_fc[1];
        }
    }
}

extern "C" void kernel_launch(void* const* d_in, const int* in_sizes, int n_in,
                              void* d_out, int out_size, void* d_ws, size_t ws_size,
                              hipStream_t stream) {
    const float* x    = (const float*)d_in[0];
    const float* W_ih = (const float*)d_in[1];
    const float* W_hh = (const float*)d_in[2];
    const float* b_ih = (const float*)d_in[3];
    const float* b_hh = (const float*)d_in[4];
    const float* W_fc = (const float*)d_in[5];
    const float* b_fc = (const float*)d_in[6];
    float* out = (float*)d_out;

    dim3 grid(BTOT / NB);   // 1024 blocks, 2 resident/CU -> 2 epochs
    dim3 block(512);
    lstm_fused_kernel<<<grid, block, 0, stream>>>(x, W_ih, W_hh, b_ih, b_hh,
                                                  W_fc, b_fc, out);
}

// Round 7
// 563.352 us; speedup vs baseline: 5.3114x; 5.3114x over previous
//
#include <hip/hip_runtime.h>

#define T 512
#define HID 64
#define BLK_B 16       // batch per block
#define TS 64          // timesteps per staged x-chunk
#define NCHUNK (T / TS)

typedef __attribute__((ext_vector_type(8))) short bf16x8;
typedef __attribute__((ext_vector_type(4))) float f32x4;

__device__ __forceinline__ unsigned short f2bf(float f) {   // RNE f32->bf16
    unsigned int u = __float_as_uint(f);
    return (unsigned short)((u + 0x7fffu + ((u >> 16) & 1u)) >> 16);
}
__device__ __forceinline__ float bf2f(unsigned short s) {
    return __uint_as_float(((unsigned int)s) << 16);
}
// split 8 f32 into bf16 hi + lo planes (hi+lo ~= f32 to ~2^-18)
__device__ __forceinline__ void split8(float4 a, float4 b, bf16x8& hi, bf16x8& lo) {
    float v[8] = {a.x, a.y, a.z, a.w, b.x, b.y, b.z, b.w};
    #pragma unroll
    for (int e = 0; e < 8; ++e) {
        unsigned short h = f2bf(v[e]);
        hi[e] = (short)h;
        lo[e] = (short)f2bf(v[e] - bf2f(h));
    }
}
__device__ __forceinline__ float fast_rcp(float x) { return __builtin_amdgcn_rcpf(x); }
__device__ __forceinline__ float sig_f(float x) { return fast_rcp(1.0f + __expf(-x)); }
__device__ __forceinline__ float th_f(float x)  { return 1.0f - 2.0f * fast_rcp(__expf(2.0f * x) + 1.0f); }

#define MFMA(a, b, c) __builtin_amdgcn_mfma_f32_16x16x32_bf16((a), (b), (c), 0, 0, 0)

// D = W · h^T per 16x16x32 bf16 tiles. src0 (A) = W rows (lane&15 = row,
// k = (lane>>4)*8+e), src1 (B) = h rows (lane&15 = batch col, same k-slicing),
// D: col = lane&15 (batch), row = (lane>>4)*4 + reg (gate-within-tile).
// Wave w owns gate cols [16w,16w+16) of all 4 gate types (tiles q=0..3) ->
// each lane holds i,f,g,o for 4 states (b = lane&15, j = 16w+(lane>>4)*4+r)
// entirely in registers.
__global__ __launch_bounds__(256) void lstm_mfma_kernel(
    const float* __restrict__ x,      // [B, T, 8]
    const float* __restrict__ W_ih,   // [256, 8]
    const float* __restrict__ W_hh,   // [256, 64]
    const float* __restrict__ b_ih,   // [256]
    const float* __restrict__ b_hh,   // [256]
    const float* __restrict__ W_fc,   // [2, 64]
    const float* __restrict__ b_fc,   // [2]
    float* __restrict__ out)          // [B, 2]
{
    // x chunk: [t][b][hi 8 bf16 | lo 8 bf16 | 8 pad] -> 48B row, 2-way banks
    __shared__ alignas(16) unsigned short xb[TS][BLK_B][24];          // 48 KB
    // h planes: [buf][hi/lo][b][72] (64 + 8 pad bf16) -> 2-way banks
    __shared__ alignas(16) unsigned short hbuf[2][2][BLK_B][72];      // 9 KB

    const int tid  = threadIdx.x;
    const int w    = tid >> 6;        // wave 0..3
    const int lane = tid & 63;
    const int colb = lane & 15;       // batch col / operand row-within-tile
    const int grp  = lane >> 4;       // k-slice group 0..3
    const int batch0 = blockIdx.x * BLK_B;

    // ---- persistent A-frags: W_hh hi/lo (2 k-tiles) + W_ih packed tile ----
#define DECL_Q(q) bf16x8 whhhi##q##_0, whhhi##q##_1, whhlo##q##_0, whhlo##q##_1, wih##q; f32x4 bias##q;
    DECL_Q(0) DECL_Q(1) DECL_Q(2) DECL_Q(3)
#undef DECL_Q

#define LOAD_Q(q) {                                                        \
        int gate = 64 * q + 16 * w + colb;                                 \
        const float* wr = W_hh + gate * 64 + grp * 8;                      \
        float4 aa = *(const float4*)(wr);                                  \
        float4 ab = *(const float4*)(wr + 4);                              \
        split8(aa, ab, whhhi##q##_0, whhlo##q##_0);                        \
        aa = *(const float4*)(wr + 32);                                    \
        ab = *(const float4*)(wr + 36);                                    \
        split8(aa, ab, whhhi##q##_1, whhlo##q##_1);                        \
        const float* wi = W_ih + gate * 8;                                 \
        float4 ia = *(const float4*)(wi);                                  \
        float4 ib = *(const float4*)(wi + 4);                              \
        bf16x8 ihi, ilo;                                                   \
        split8(ia, ib, ihi, ilo);                                          \
        /* A k-slices of x-tile: grp0,1 -> Wih_hi (pairs x_hi,x_lo),       \
           grp2 -> Wih_lo (pairs x_hi), grp3 -> 0 */                       \
        bf16x8 zz = {0,0,0,0,0,0,0,0};                                     \
        wih##q = (grp <= 1) ? ihi : ((grp == 2) ? ilo : zz);               \
        int gb = 64 * q + 16 * w + grp * 4;                                \
        bias##q.x = b_ih[gb + 0] + b_hh[gb + 0];                           \
        bias##q.y = b_ih[gb + 1] + b_hh[gb + 1];                           \
        bias##q.z = b_ih[gb + 2] + b_hh[gb + 2];                           \
        bias##q.w = b_ih[gb + 3] + b_hh[gb + 3];                           \
    }
    LOAD_Q(0) LOAD_Q(1) LOAD_Q(2) LOAD_Q(3)
#undef LOAD_Q

    // zero h double-buffer 0 (both planes): 2304 shorts / 256 thr = 9 each
    unsigned short* hflat = &hbuf[0][0][0][0];
    #pragma unroll
    for (int i = 0; i < 9; ++i) hflat[tid * 9 + i] = 0;

    f32x4 cst = {0.0f, 0.0f, 0.0f, 0.0f};    // c for 4 owned states

    // precomputed per-lane LDS short-offsets
    const int rd_base = colb * 72 + grp * 8;                 // B-frag read
    const int wr_base = colb * 72 + 16 * w + grp * 4;        // h write (j0)
    const int xoff    = colb * 24 + ((grp == 1) ? 8 : 0);    // x B-frag read

    int cur = 0;
    #pragma unroll 1
    for (int tc = 0; tc < NCHUNK; ++tc) {
        // ---- stage + convert x chunk: thread -> (b = tid>>4, 4 t's) ----
        {
            int sb = tid >> 4, st = tid & 15;
            #pragma unroll
            for (int r = 0; r < 4; ++r) {
                int t = st + r * 16;
                const float4* xg = (const float4*)(x +
                    ((size_t)(batch0 + sb) * T + (size_t)tc * TS + t) * 8);
                bf16x8 hi, lo;
                split8(xg[0], xg[1], hi, lo);
                *(bf16x8*)&xb[t][sb][0] = hi;
                *(bf16x8*)&xb[t][sb][8] = lo;
            }
        }
        __syncthreads();   // also covers hbuf[0] zero-init at tc==0

        #pragma unroll 1
        for (int tt = 0; tt < TS; ++tt) {
            // ---- B-frags: h hi/lo (2 k-tiles each) + x ----
            const unsigned short* hc = hflat + cur * 2304;
            bf16x8 bh0 = *(const bf16x8*)(hc + rd_base);
            bf16x8 bh1 = *(const bf16x8*)(hc + rd_base + 32);
            bf16x8 bl0 = *(const bf16x8*)(hc + 1152 + rd_base);
            bf16x8 bl1 = *(const bf16x8*)(hc + 1152 + rd_base + 32);
            bf16x8 bx  = *(const bf16x8*)(&xb[0][0][0] + tt * 384 + xoff);

            // ---- 7 MFMA per gate tile: hi*hi(2) + hi*lo(2) + lo*hi(2) + x ----
            f32x4 a0 = {0,0,0,0}, a1 = {0,0,0,0}, a2 = {0,0,0,0}, a3 = {0,0,0,0};
#define QMM(q, acc)                                   \
            acc = MFMA(whhhi##q##_0, bh0, acc);       \
            acc = MFMA(whhhi##q##_1, bh1, acc);       \
            acc = MFMA(whhhi##q##_0, bl0, acc);       \
            acc = MFMA(whhhi##q##_1, bl1, acc);       \
            acc = MFMA(whhlo##q##_0, bh0, acc);       \
            acc = MFMA(whhlo##q##_1, bh1, acc);       \
            acc = MFMA(wih##q, bx, acc);
            QMM(0, a0) QMM(1, a1) QMM(2, a2) QMM(3, a3)
#undef QMM

            a0 += bias0; a1 += bias1; a2 += bias2; a3 += bias3;

            // ---- activations (tile q == gate type: i,f,g,o) ----
            f32x4 gi, gf, gg, go;
            gi.x = sig_f(a0.x); gi.y = sig_f(a0.y); gi.z = sig_f(a0.z); gi.w = sig_f(a0.w);
            gf.x = sig_f(a1.x); gf.y = sig_f(a1.y); gf.z = sig_f(a1.z); gf.w = sig_f(a1.w);
            gg.x = th_f(a2.x);  gg.y = th_f(a2.y);  gg.z = th_f(a2.z);  gg.w = th_f(a2.w);
            go.x = sig_f(a3.x); go.y = sig_f(a3.y); go.z = sig_f(a3.z); go.w = sig_f(a3.w);

            // ---- state update (all in registers) ----
            cst.x = fmaf(gf.x, cst.x, gi.x * gg.x);
            cst.y = fmaf(gf.y, cst.y, gi.y * gg.y);
            cst.z = fmaf(gf.z, cst.z, gi.z * gg.z);
            cst.w = fmaf(gf.w, cst.w, gi.w * gg.w);
            float h0 = go.x * th_f(cst.x);
            float h1 = go.y * th_f(cst.y);
            float h2 = go.z * th_f(cst.z);
            float h3 = go.w * th_f(cst.w);

            // ---- split h -> bf16 hi/lo, write 4 consecutive j as b64 ----
            unsigned short s0 = f2bf(h0), s1 = f2bf(h1), s2 = f2bf(h2), s3 = f2bf(h3);
            unsigned short t0 = f2bf(h0 - bf2f(s0)), t1 = f2bf(h1 - bf2f(s1));
            unsigned short t2 = f2bf(h2 - bf2f(s2)), t3 = f2bf(h3 - bf2f(s3));
            unsigned short* hw = hflat + (cur ^ 1) * 2304;
            uint2 hiw, low;
            hiw.x = (unsigned)s0 | ((unsigned)s1 << 16);
            hiw.y = (unsigned)s2 | ((unsigned)s3 << 16);
            low.x = (unsigned)t0 | ((unsigned)t1 << 16);
            low.y = (unsigned)t2 | ((unsigned)t3 << 16);
            *(uint2*)(hw + wr_base)        = hiw;
            *(uint2*)(hw + 1152 + wr_base) = low;

            __syncthreads();   // single barrier per step (double-buffered h)
            cur ^= 1;
        }
    }

    // ---- final FC: thread -> (b = tid>>4, 4 j's); reduce over 16 threads ----
    {
        const unsigned short* hf = hflat + cur * 2304;
        int b = tid >> 4, q4 = (tid & 15) * 4;
        const unsigned short* ph = hf + b * 72 + q4;
        const unsigned short* pl = ph + 1152;
        float h0 = bf2f(ph[0]) + bf2f(pl[0]);
        float h1 = bf2f(ph[1]) + bf2f(pl[1]);
        float h2 = bf2f(ph[2]) + bf2f(pl[2]);
        float h3 = bf2f(ph[3]) + bf2f(pl[3]);
        float s0 = h0 * W_fc[q4] + h1 * W_fc[q4 + 1] + h2 * W_fc[q4 + 2] + h3 * W_fc[q4 + 3];
        float s1 = h0 * W_fc[64 + q4] + h1 * W_fc[64 + q4 + 1] + h2 * W_fc[64 + q4 + 2] + h3 * W_fc[64 + q4 + 3];
        #pragma unroll
        for (int off = 1; off < 16; off <<= 1) {
            s0 += __shfl_xor(s0, off, 64);
            s1 += __shfl_xor(s1, off, 64);
        }
        if ((tid & 15) == 0) {
            out[(size_t)(batch0 + b) * 2 + 0] = s0 + b_fc[0];
            out[(size_t)(batch0 + b) * 2 + 1] = s1 + b_fc[1];
        }
    }
}

extern "C" void kernel_launch(void* const* d_in, const int* in_sizes, int n_in,
                              void* d_out, int out_size, void* d_ws, size_t ws_size,
                              hipStream_t stream) {
    const float* x    = (const float*)d_in[0];
    const float* W_ih = (const float*)d_in[1];
    const float* W_hh = (const float*)d_in[2];
    const float* b_ih = (const float*)d_in[3];
    const float* b_hh = (const float*)d_in[4];
    const float* W_fc = (const float*)d_in[5];
    const float* b_fc = (const float*)d_in[6];
    float* out = (float*)d_out;

    dim3 grid(8192 / BLK_B);   // 512 blocks = 2 per CU (forced by 57 KB LDS)
    dim3 block(256);
    lstm_mfma_kernel<<<grid, block, 0, stream>>>(x, W_ih, W_hh, b_ih, b_hh,
                                                 W_fc, b_fc, out);
}

// Round 8
// 439.623 us; speedup vs baseline: 6.8062x; 1.2814x over previous
//
#include <hip/hip_runtime.h>

#define T 512
#define HID 64
#define BLK_B 16       // batch per block
#define TS 64          // timesteps per staged x-chunk
#define NCHUNK (T / TS)
#define INV2048 4.8828125e-4f

typedef __attribute__((ext_vector_type(8))) _Float16 f16x8;
typedef __attribute__((ext_vector_type(4))) _Float16 f16x4;
typedef __attribute__((ext_vector_type(4))) float f32x4;

__device__ __forceinline__ float fast_rcp(float x) { return __builtin_amdgcn_rcpf(x); }
__device__ __forceinline__ float sig_f(float x) { return fast_rcp(1.0f + __expf(-x)); }
__device__ __forceinline__ float th_f(float x)  { return 1.0f - 2.0f * fast_rcp(__expf(2.0f * x) + 1.0f); }

#define MFMA(a, b, c) __builtin_amdgcn_mfma_f32_16x16x32_f16((a), (b), (c), 0, 0, 0)

// split 8 f32 into f16 hi + (residual * 2048) f16 lo.
// |W| <= 0.125 -> residual <= 6.1e-5 (f16 denormal zone!); *2048 renormalizes.
__device__ __forceinline__ void splitf16(const float* p, f16x8& hi, f16x8& lo) {
    #pragma unroll
    for (int e = 0; e < 8; ++e) {
        float v = p[e];
        _Float16 h = (_Float16)v;
        hi[e] = h;
        lo[e] = (_Float16)((v - (float)h) * 2048.0f);
    }
}

// D = W · h^T per 16x16x32 f16 tiles (same verified lane mapping as round 7:
// A lane&15 = gate row, k = grp*8+e; B lane&15 = batch col; D col = lane&15,
// row = grp*4 + reg). W ~= W_hi + W_lo/2048 (exact to ~2^-22); h single f16
// plane (random ~2.4e-4/step quantization; sqrt(512)-walk ~1e-3 << 4.9e-3).
__global__ __launch_bounds__(256, 2) void lstm_mfma_kernel(
    const float* __restrict__ x,      // [B, T, 8]
    const float* __restrict__ W_ih,   // [256, 8]
    const float* __restrict__ W_hh,   // [256, 64]
    const float* __restrict__ b_ih,   // [256]
    const float* __restrict__ b_hh,   // [256]
    const float* __restrict__ W_fc,   // [2, 64]
    const float* __restrict__ b_fc,   // [2]
    float* __restrict__ out)          // [B, 2]
{
    // Single 56KB arena (one USED object -> full size allocated; a separate
    // pad array gets DCE'd, round-6 evidence). 56KB -> occupancy target
    // 2 blocks/CU -> 2 waves/SIMD -> 256-VGPR budget (rounds 3-7 model).
    __shared__ alignas(16) _Float16 arena[28672];            // 56 KB
    _Float16* xb    = arena;                  // [TS][16][8]  f16 x chunk
    _Float16* hbase = arena + TS * BLK_B * 8; // [2][16][72]  h double-buffer

    const int tid  = threadIdx.x;
    const int w    = tid >> 6;        // wave 0..3 -> gate cols [16w,16w+16)
    const int lane = tid & 63;
    const int colb = lane & 15;       // batch col / A gate row
    const int grp  = lane >> 4;       // k-slice group 0..3
    const int batch0 = blockIdx.x * BLK_B;

    // ---- persistent A-frags: W_hh f16 hi + scaled-lo (2 k-tiles), W_ih ----
#define DECL_Q(q) f16x8 whi##q##_0, whi##q##_1, wlo##q##_0, wlo##q##_1, wih##q; f32x4 bias##q;
    DECL_Q(0) DECL_Q(1) DECL_Q(2) DECL_Q(3)
#undef DECL_Q

    f16x8 zz;
    #pragma unroll
    for (int e = 0; e < 8; ++e) zz[e] = (_Float16)0.0f;

#define LOAD_Q(q) {                                                        \
        int gate = 64 * q + 16 * w + colb;                                 \
        const float* wr = W_hh + gate * 64 + grp * 8;                      \
        splitf16(wr,      whi##q##_0, wlo##q##_0);                         \
        splitf16(wr + 32, whi##q##_1, wlo##q##_1);                         \
        const float* wi = W_ih + gate * 8;                                 \
        f16x8 ih;                                                          \
        _Pragma("unroll")                                                  \
        for (int e = 0; e < 8; ++e) ih[e] = (_Float16)wi[e];               \
        wih##q = (grp == 0) ? ih : zz;   /* x term only in k-slot group 0 */ \
        int gb = 64 * q + 16 * w + grp * 4;                                \
        bias##q.x = b_ih[gb + 0] + b_hh[gb + 0];                           \
        bias##q.y = b_ih[gb + 1] + b_hh[gb + 1];                           \
        bias##q.z = b_ih[gb + 2] + b_hh[gb + 2];                           \
        bias##q.w = b_ih[gb + 3] + b_hh[gb + 3];                           \
    }
    LOAD_Q(0) LOAD_Q(1) LOAD_Q(2) LOAD_Q(3)
#undef LOAD_Q

    // zero both h buffers: 2304 halves / 256 threads = 9 each
    #pragma unroll
    for (int i = 0; i < 9; ++i) hbase[tid * 9 + i] = (_Float16)0.0f;

    f32x4 cst = {0.0f, 0.0f, 0.0f, 0.0f};    // c for 4 owned states
    const f32x4 z4 = {0.0f, 0.0f, 0.0f, 0.0f};

    int cur = 0;
    #pragma unroll 1
    for (int tc = 0; tc < NCHUNK; ++tc) {
        // ---- stage + convert x chunk (prev chunk's reads ended at last
        //      step's barrier; h-init at tc=0 covered by barrier below) ----
        {
            int sb = tid >> 4, st = tid & 15;
            #pragma unroll
            for (int r = 0; r < 4; ++r) {
                int t = st + r * 16;
                const float* xg = x + ((size_t)(batch0 + sb) * T + (size_t)tc * TS + t) * 8;
                f16x8 v;
                #pragma unroll
                for (int e = 0; e < 8; ++e) v[e] = (_Float16)xg[e];
                *(f16x8*)(xb + (t * BLK_B + sb) * 8) = v;
            }
        }
        __syncthreads();

        #pragma unroll 1
        for (int tt = 0; tt < TS; ++tt) {
            // ---- B-frags: h (single f16 plane, 2 k-tiles) + x ----
            const _Float16* hc = hbase + cur * 1152;
            f16x8 bh0 = *(const f16x8*)(hc + colb * 72 + grp * 8);
            f16x8 bh1 = *(const f16x8*)(hc + colb * 72 + 32 + grp * 8);
            f16x8 bx  = *(const f16x8*)(xb + (tt * BLK_B + colb) * 8);

            // ---- 5 MFMA per gate tile: x(C-in=bias) + hi(2) + scaled-lo(2) ----
#define QMM(q, acc)                                           \
            f32x4 acc = MFMA(wih##q, bx, bias##q);            \
            acc = MFMA(whi##q##_0, bh0, acc);                 \
            acc = MFMA(whi##q##_1, bh1, acc);                 \
            {                                                 \
                f32x4 al = MFMA(wlo##q##_0, bh0, z4);         \
                al = MFMA(wlo##q##_1, bh1, al);               \
                acc.x = fmaf(al.x, INV2048, acc.x);           \
                acc.y = fmaf(al.y, INV2048, acc.y);           \
                acc.z = fmaf(al.z, INV2048, acc.z);           \
                acc.w = fmaf(al.w, INV2048, acc.w);           \
            }
            QMM(0, a0) QMM(1, a1) QMM(2, a2) QMM(3, a3)
#undef QMM

            // ---- activations (tile q == gate type: i,f,g,o) ----
            f32x4 gi, gf, gg, go;
            gi.x = sig_f(a0.x); gi.y = sig_f(a0.y); gi.z = sig_f(a0.z); gi.w = sig_f(a0.w);
            gf.x = sig_f(a1.x); gf.y = sig_f(a1.y); gf.z = sig_f(a1.z); gf.w = sig_f(a1.w);
            gg.x = th_f(a2.x);  gg.y = th_f(a2.y);  gg.z = th_f(a2.z);  gg.w = th_f(a2.w);
            go.x = sig_f(a3.x); go.y = sig_f(a3.y); go.z = sig_f(a3.z); go.w = sig_f(a3.w);

            // ---- state update (registers) ----
            cst.x = fmaf(gf.x, cst.x, gi.x * gg.x);
            cst.y = fmaf(gf.y, cst.y, gi.y * gg.y);
            cst.z = fmaf(gf.z, cst.z, gi.z * gg.z);
            cst.w = fmaf(gf.w, cst.w, gi.w * gg.w);
            float h0 = go.x * th_f(cst.x);
            float h1 = go.y * th_f(cst.y);
            float h2 = go.z * th_f(cst.z);
            float h3 = go.w * th_f(cst.w);

            // ---- h -> single f16 plane, one b64 store of 4 consecutive j ----
            {
                _Float16* hw = hbase + (cur ^ 1) * 1152 + colb * 72 + 16 * w + grp * 4;
                f16x4 hv;
                hv[0] = (_Float16)h0; hv[1] = (_Float16)h1;
                hv[2] = (_Float16)h2; hv[3] = (_Float16)h3;
                *(f16x4*)hw = hv;
            }

            __syncthreads();   // single barrier per step (double-buffered h)
            cur ^= 1;
        }
    }

    // ---- final FC: thread -> (b = tid>>4, 4 j's); reduce over 16 threads ----
    {
        const _Float16* ph = hbase + cur * 1152 + (tid >> 4) * 72 + (tid & 15) * 4;
        int b = tid >> 4, q4 = (tid & 15) * 4;
        float h0 = (float)ph[0];
        float h1 = (float)ph[1];
        float h2 = (float)ph[2];
        float h3 = (float)ph[3];
        float s0 = h0 * W_fc[q4] + h1 * W_fc[q4 + 1] + h2 * W_fc[q4 + 2] + h3 * W_fc[q4 + 3];
        float s1 = h0 * W_fc[64 + q4] + h1 * W_fc[64 + q4 + 1] + h2 * W_fc[64 + q4 + 2] + h3 * W_fc[64 + q4 + 3];
        #pragma unroll
        for (int off = 1; off < 16; off <<= 1) {
            s0 += __shfl_xor(s0, off, 64);
            s1 += __shfl_xor(s1, off, 64);
        }
        if ((tid & 15) == 0) {
            out[(size_t)(batch0 + b) * 2 + 0] = s0 + b_fc[0];
            out[(size_t)(batch0 + b) * 2 + 1] = s1 + b_fc[1];
        }
    }
}

extern "C" void kernel_launch(void* const* d_in, const int* in_sizes, int n_in,
                              void* d_out, int out_size, void* d_ws, size_t ws_size,
                              hipStream_t stream) {
    const float* x    = (const float*)d_in[0];
    const float* W_ih = (const float*)d_in[1];
    const float* W_hh = (const float*)d_in[2];
    const float* b_ih = (const float*)d_in[3];
    const float* b_hh = (const float*)d_in[4];
    const float* W_fc = (const float*)d_in[5];
    const float* b_fc = (const float*)d_in[6];
    float* out = (float*)d_out;

    dim3 grid(8192 / BLK_B);   // 512 blocks = 2 per CU
    dim3 block(256);
    lstm_mfma_kernel<<<grid, block, 0, stream>>>(x, W_ih, W_hh, b_ih, b_hh,
                                                 W_fc, b_fc, out);
}

// Round 9
// 368.261 us; speedup vs baseline: 8.1251x; 1.1938x over previous
//
#include <hip/hip_runtime.h>

#define T 512
#define HID 64
#define BLK_B 16       // batch per block
#define TS 64          // timesteps per staged x-chunk
#define NCHUNK (T / TS)

typedef __attribute__((ext_vector_type(8))) _Float16 f16x8;
typedef __attribute__((ext_vector_type(4))) _Float16 f16x4;
typedef __attribute__((ext_vector_type(4))) float f32x4;

__device__ __forceinline__ float fast_rcp(float x) { return __builtin_amdgcn_rcpf(x); }
__device__ __forceinline__ float sig_f(float x) { return fast_rcp(1.0f + __expf(-x)); }
__device__ __forceinline__ float th_f(float x)  { return 1.0f - 2.0f * fast_rcp(__expf(2.0f * x) + 1.0f); }

#define MFMA(a, b, c) __builtin_amdgcn_mfma_f32_16x16x32_f16((a), (b), (c), 0, 0, 0)

// D = W · h^T per 16x16x32 f16 tiles (verified lane mapping, rounds 7-8:
// A lane&15 = gate row, k = grp*8+e; B lane&15 = batch col; D col = lane&15,
// row = grp*4 + reg). Round-9 change: W_hh single f16 plane (RNE, rel err
// 2^-12; error analysis in round-9 notes -> ~1.5-3e-3 final, threshold
// 4.94e-3). 12 MFMA/wave-step = K-minimal (ceil(72/32) * 4 gate tiles).
__global__ __launch_bounds__(256, 2) void lstm_mfma_kernel(
    const float* __restrict__ x,      // [B, T, 8]
    const float* __restrict__ W_ih,   // [256, 8]
    const float* __restrict__ W_hh,   // [256, 64]
    const float* __restrict__ b_ih,   // [256]
    const float* __restrict__ b_hh,   // [256]
    const float* __restrict__ W_fc,   // [2, 64]
    const float* __restrict__ b_fc,   // [2]
    float* __restrict__ out)          // [B, 2]
{
    // Single 56KB arena: keeps backend occupancy target at 2 blocks/CU ->
    // 256-VGPR budget -> no spill (occupancy-target model, rounds 3-8).
    __shared__ alignas(16) _Float16 arena[28672];            // 56 KB
    _Float16* xb    = arena;                  // [TS][16][8]  f16 x chunk
    _Float16* hbase = arena + TS * BLK_B * 8; // [2][16][72]  h double-buffer

    const int tid  = threadIdx.x;
    const int w    = tid >> 6;        // wave 0..3 -> gate cols [16w,16w+16)
    const int lane = tid & 63;
    const int colb = lane & 15;       // batch col / A gate row
    const int grp  = lane >> 4;       // k-slice group 0..3
    const int batch0 = blockIdx.x * BLK_B;

    // ---- persistent A-frags: W_hh f16 (2 k-tiles), W_ih packed tile ----
#define DECL_Q(q) f16x8 whi##q##_0, whi##q##_1, wih##q; f32x4 bias##q;
    DECL_Q(0) DECL_Q(1) DECL_Q(2) DECL_Q(3)
#undef DECL_Q

    f16x8 zz;
    #pragma unroll
    for (int e = 0; e < 8; ++e) zz[e] = (_Float16)0.0f;

#define LOAD_Q(q) {                                                        \
        int gate = 64 * q + 16 * w + colb;                                 \
        const float* wr = W_hh + gate * 64 + grp * 8;                      \
        _Pragma("unroll")                                                  \
        for (int e = 0; e < 8; ++e) {                                      \
            whi##q##_0[e] = (_Float16)wr[e];                               \
            whi##q##_1[e] = (_Float16)wr[32 + e];                          \
        }                                                                  \
        const float* wi = W_ih + gate * 8;                                 \
        f16x8 ih;                                                          \
        _Pragma("unroll")                                                  \
        for (int e = 0; e < 8; ++e) ih[e] = (_Float16)wi[e];               \
        wih##q = (grp == 0) ? ih : zz;   /* x term only in k-slot group 0 */ \
        int gb = 64 * q + 16 * w + grp * 4;                                \
        bias##q.x = b_ih[gb + 0] + b_hh[gb + 0];                           \
        bias##q.y = b_ih[gb + 1] + b_hh[gb + 1];                           \
        bias##q.z = b_ih[gb + 2] + b_hh[gb + 2];                           \
        bias##q.w = b_ih[gb + 3] + b_hh[gb + 3];                           \
    }
    LOAD_Q(0) LOAD_Q(1) LOAD_Q(2) LOAD_Q(3)
#undef LOAD_Q

    // zero both h buffers: 2304 halves / 256 threads = 9 each
    #pragma unroll
    for (int i = 0; i < 9; ++i) hbase[tid * 9 + i] = (_Float16)0.0f;

    f32x4 cst = {0.0f, 0.0f, 0.0f, 0.0f};    // c for 4 owned states

    int cur = 0;
    #pragma unroll 1
    for (int tc = 0; tc < NCHUNK; ++tc) {
        // ---- stage + convert x chunk ----
        {
            int sb = tid >> 4, st = tid & 15;
            #pragma unroll
            for (int r = 0; r < 4; ++r) {
                int t = st + r * 16;
                const float* xg = x + ((size_t)(batch0 + sb) * T + (size_t)tc * TS + t) * 8;
                f16x8 v;
                #pragma unroll
                for (int e = 0; e < 8; ++e) v[e] = (_Float16)xg[e];
                *(f16x8*)(xb + (t * BLK_B + sb) * 8) = v;
            }
        }
        __syncthreads();

        #pragma unroll 1
        for (int tt = 0; tt < TS; ++tt) {
            // ---- B-frags: h (single f16 plane, 2 k-tiles) + x ----
            const _Float16* hc = hbase + cur * 1152;
            f16x8 bh0 = *(const f16x8*)(hc + colb * 72 + grp * 8);
            f16x8 bh1 = *(const f16x8*)(hc + colb * 72 + 32 + grp * 8);
            f16x8 bx  = *(const f16x8*)(xb + (tt * BLK_B + colb) * 8);

            // ---- 3 MFMA per gate tile: x (C-in = bias) -> hi0 -> hi1 ----
#define QMM(q, acc)                                           \
            f32x4 acc = MFMA(wih##q, bx, bias##q);            \
            acc = MFMA(whi##q##_0, bh0, acc);                 \
            acc = MFMA(whi##q##_1, bh1, acc);
            QMM(0, a0) QMM(1, a1) QMM(2, a2) QMM(3, a3)
#undef QMM

            // ---- activations (tile q == gate type: i,f,g,o) ----
            f32x4 gi, gf, gg, go;
            gi.x = sig_f(a0.x); gi.y = sig_f(a0.y); gi.z = sig_f(a0.z); gi.w = sig_f(a0.w);
            gf.x = sig_f(a1.x); gf.y = sig_f(a1.y); gf.z = sig_f(a1.z); gf.w = sig_f(a1.w);
            gg.x = th_f(a2.x);  gg.y = th_f(a2.y);  gg.z = th_f(a2.z);  gg.w = th_f(a2.w);
            go.x = sig_f(a3.x); go.y = sig_f(a3.y); go.z = sig_f(a3.z); go.w = sig_f(a3.w);

            // ---- state update (registers) ----
            cst.x = fmaf(gf.x, cst.x, gi.x * gg.x);
            cst.y = fmaf(gf.y, cst.y, gi.y * gg.y);
            cst.z = fmaf(gf.z, cst.z, gi.z * gg.z);
            cst.w = fmaf(gf.w, cst.w, gi.w * gg.w);
            float h0 = go.x * th_f(cst.x);
            float h1 = go.y * th_f(cst.y);
            float h2 = go.z * th_f(cst.z);
            float h3 = go.w * th_f(cst.w);

            // ---- h -> f16 plane, one b64 store of 4 consecutive j ----
            {
                _Float16* hw = hbase + (cur ^ 1) * 1152 + colb * 72 + 16 * w + grp * 4;
                f16x4 hv;
                hv[0] = (_Float16)h0; hv[1] = (_Float16)h1;
                hv[2] = (_Float16)h2; hv[3] = (_Float16)h3;
                *(f16x4*)hw = hv;
            }

            __syncthreads();   // single barrier per step (double-buffered h)
            cur ^= 1;
        }
    }

    // ---- final FC: thread -> (b = tid>>4, 4 j's); reduce over 16 threads ----
    {
        const _Float16* ph = hbase + cur * 1152 + (tid >> 4) * 72 + (tid & 15) * 4;
        int b = tid >> 4, q4 = (tid & 15) * 4;
        float h0 = (float)ph[0];
        float h1 = (float)ph[1];
        float h2 = (float)ph[2];
        float h3 = (float)ph[3];
        float s0 = h0 * W_fc[q4] + h1 * W_fc[q4 + 1] + h2 * W_fc[q4 + 2] + h3 * W_fc[q4 + 3];
        float s1 = h0 * W_fc[64 + q4] + h1 * W_fc[64 + q4 + 1] + h2 * W_fc[64 + q4 + 2] + h3 * W_fc[64 + q4 + 3];
        #pragma unroll
        for (int off = 1; off < 16; off <<= 1) {
            s0 += __shfl_xor(s0, off, 64);
            s1 += __shfl_xor(s1, off, 64);
        }
        if ((tid & 15) == 0) {
            out[(size_t)(batch0 + b) * 2 + 0] = s0 + b_fc[0];
            out[(size_t)(batch0 + b) * 2 + 1] = s1 + b_fc[1];
        }
    }
}

extern "C" void kernel_launch(void* const* d_in, const int* in_sizes, int n_in,
                              void* d_out, int out_size, void* d_ws, size_t ws_size,
                              hipStream_t stream) {
    const float* x    = (const float*)d_in[0];
    const float* W_ih = (const float*)d_in[1];
    const float* W_hh = (const float*)d_in[2];
    const float* b_ih = (const float*)d_in[3];
    const float* b_hh = (const float*)d_in[4];
    const float* W_fc = (const float*)d_in[5];
    const float* b_fc = (const float*)d_in[6];
    float* out = (float*)d_out;

    dim3 grid(8192 / BLK_B);   // 512 blocks = 2 per CU
    dim3 block(256);
    lstm_mfma_kernel<<<grid, block, 0, stream>>>(x, W_ih, W_hh, b_ih, b_hh,
                                                 W_fc, b_fc, out);
}